// Round 3
// baseline (275.936 us; speedup 1.0000x reference)
//
#include <hip/hip_runtime.h>
#include <hip/hip_bf16.h>

#define EMB 128
#define HID 11
#define UNROLL 4

typedef float f32x2 __attribute__((ext_vector_type(2)));
typedef float f32x4 __attribute__((ext_vector_type(4)));

// tanh(x) = sign(x) * (1 - 2/(exp(2|x|)+1)); v_exp_f32 + v_rcp_f32 fast path.
__device__ __forceinline__ float fast_tanh(float x) {
    float ax = fabsf(x);
    float e  = __expf(2.0f * ax);
    float r  = 1.0f - 2.0f * __builtin_amdgcn_rcpf(e + 1.0f);
    return copysignf(r, x);
}

// Wave layout: lanes 0..31 -> token 2w, lanes 32..63 -> token 2w+1.
// Lane covers 4 emb columns, c0 = (lane&31)*4. One fast-tanh pass per token
// (lanes sub<11), h broadcast via __shfl within the half-wave.
// 4-way unrolled grid-stride: all scalar loads + 4 emb gathers issued before
// compute (MLP); W2 accumulation as f32x2 vector math so LLVM can emit
// v_pk_fma_f32 (halves the dominant FMA issue). NT stores keep emb in L2.
__global__ __launch_bounds__(256, 4) void tabenc_kernel(
    const float* __restrict__ value,
    const int*   __restrict__ var_id,
    const int*   __restrict__ cmask,
    const float* __restrict__ W1,
    const float* __restrict__ b1,
    const float* __restrict__ W2,
    const float* __restrict__ emb,
    float*       __restrict__ out_sum,
    float*       __restrict__ out_pm,
    int n_tokens)
{
    const int tid  = threadIdx.x;
    const int lane = tid & 63;
    const int half = lane >> 5;
    const int sub  = lane & 31;
    const int sb   = lane & 32;      // shfl source base for this half-wave
    const int c0   = sub << 2;

    // W2 fragment as f32x2 halves (encourage v_pk_fma_f32).
    f32x2 w2lo[HID], w2hi[HID];
#pragma unroll
    for (int h = 0; h < HID; ++h) {
        f32x4 t = *reinterpret_cast<const f32x4*>(W2 + h * EMB + c0);
        w2lo[h] = (f32x2){t.x, t.y};
        w2hi[h] = (f32x2){t.z, t.w};
    }

    float w1v = 0.0f, b1v = 0.0f;
    if (sub < HID) { w1v = W1[sub]; b1v = b1[sub]; }

    const int gwave  = (blockIdx.x << 2) + (tid >> 6);
    const int nwaves = gridDim.x << 2;
    const int nwU    = nwaves * UNROLL;
    const int npair  = (n_tokens + 1) >> 1;
    const int tmax   = n_tokens - 1;

    for (int w = gwave; w < npair; w += nwU) {
        int   tok[UNROLL];
        bool  act[UNROLL];
        float v[UNROLL];
        int   id[UNROLL];
        float fm[UNROLL];

#pragma unroll
        for (int k = 0; k < UNROLL; ++k) {
            const int wk = w + k * nwaves;
            act[k] = (wk < npair);
            int t = 2 * wk + half;
            if (t > tmax) t = tmax;
            tok[k] = t;
            v[k]  = value[t];
            id[k] = var_id[t];
            fm[k] = (float)cmask[t];
        }

        f32x4 e[UNROLL];
#pragma unroll
        for (int k = 0; k < UNROLL; ++k)
            e[k] = *reinterpret_cast<const f32x4*>(emb + (long)id[k] * EMB + c0);

        float hv[UNROLL];
#pragma unroll
        for (int k = 0; k < UNROLL; ++k)
            hv[k] = fast_tanh(fmaf(v[k], w1v, b1v));

        f32x2 alo[UNROLL], ahi[UNROLL];
#pragma unroll
        for (int k = 0; k < UNROLL; ++k) {
            alo[k] = (f32x2){0.f, 0.f};
            ahi[k] = (f32x2){0.f, 0.f};
        }

#pragma unroll
        for (int hh = 0; hh < HID; ++hh) {
#pragma unroll
            for (int k = 0; k < UNROLL; ++k) {
                const float kk = __shfl(hv[k], sb + hh, 64);
                const f32x2 k2 = (f32x2){kk, kk};
                alo[k] += k2 * w2lo[hh];
                ahi[k] += k2 * w2hi[hh];
            }
        }

#pragma unroll
        for (int k = 0; k < UNROLL; ++k) {
            if (!act[k]) continue;
            const f32x2 m2  = (f32x2){fm[k], fm[k]};
            const f32x2 olo = alo[k] * m2 + (f32x2){e[k].x, e[k].y};
            const f32x2 ohi = ahi[k] * m2 + (f32x2){e[k].z, e[k].w};
            const f32x4 o   = (f32x4){olo.x, olo.y, ohi.x, ohi.y};
            __builtin_nontemporal_store(o,
                reinterpret_cast<f32x4*>(out_sum + (long)tok[k] * EMB + c0));
            if (sub == 0)
                __builtin_nontemporal_store((id[k] > 0) ? 1.0f : 0.0f,
                                            out_pm + tok[k]);
        }
    }
}

extern "C" void kernel_launch(void* const* d_in, const int* in_sizes, int n_in,
                              void* d_out, int out_size, void* d_ws, size_t ws_size,
                              hipStream_t stream) {
    const float* value  = (const float*)d_in[0];
    const int*   var_id = (const int*)  d_in[1];
    const int*   cmask  = (const int*)  d_in[2];
    const float* W1     = (const float*)d_in[3];
    const float* b1     = (const float*)d_in[4];
    const float* W2     = (const float*)d_in[5];
    const float* emb    = (const float*)d_in[6];

    const int n_tokens = in_sizes[0];              // 4096*200 = 819200
    float* out_sum = (float*)d_out;                // [n_tokens, 128]
    float* out_pm  = (float*)d_out + (long long)n_tokens * EMB;  // [n_tokens]

    const int waves_needed  = (n_tokens + 1) / 2;
    const int blocks_needed = (waves_needed + 3) / 4;
    const int grid = blocks_needed < 2048 ? blocks_needed : 2048;

    tabenc_kernel<<<grid, 256, 0, stream>>>(value, var_id, cmask, W1, b1, W2,
                                            emb, out_sum, out_pm, n_tokens);
}

// Round 4
// 97.748 us; speedup vs baseline: 2.8229x; 2.8229x over previous
//
#include <hip/hip_runtime.h>
#include <hip/hip_bf16.h>

#define EMB 128
#define HID 11
#define UNROLL 4

typedef float f32x4 __attribute__((ext_vector_type(4)));

// tanh(x) = sign(x) * (1 - 2/(exp(2|x|)+1)); v_exp_f32 + v_rcp_f32 fast path.
__device__ __forceinline__ float fast_tanh(float x) {
    float ax = fabsf(x);
    float e  = __expf(2.0f * ax);
    float r  = 1.0f - 2.0f * __builtin_amdgcn_rcpf(e + 1.0f);
    return copysignf(r, x);
}

// Wave layout: lanes 0..31 -> token 2w, lanes 32..63 -> token 2w+1.
// Lane covers 4 emb columns (float4), c0 = (lane&31)*4. One fast-tanh pass
// per token (lanes sub<11), h broadcast via __shfl within the half-wave.
// 4-way unrolled grid-stride: all scalar loads + 4 emb gathers in flight
// before the FMA block. __launch_bounds__(256,2): min 2 waves/EU -> VGPR cap
// 256, so the ~110 live regs (W2 frag 44 + unroll state) do NOT spill.
// (R3 lesson: (256,4) made the allocator target 64 VGPRs and spill ~70 MB of
// scratch traffic per call -> 3x slowdown.)
__global__ __launch_bounds__(256, 2) void tabenc_kernel(
    const float* __restrict__ value,
    const int*   __restrict__ var_id,
    const int*   __restrict__ cmask,
    const float* __restrict__ W1,
    const float* __restrict__ b1,
    const float* __restrict__ W2,
    const float* __restrict__ emb,
    float*       __restrict__ out_sum,
    float*       __restrict__ out_pm,
    int n_tokens)
{
    const int tid  = threadIdx.x;
    const int lane = tid & 63;
    const int half = lane >> 5;
    const int sub  = lane & 31;
    const int sb   = lane & 32;      // shfl source base for this half-wave
    const int c0   = sub << 2;

    f32x4 w2[HID];
#pragma unroll
    for (int h = 0; h < HID; ++h)
        w2[h] = *reinterpret_cast<const f32x4*>(W2 + h * EMB + c0);

    float w1v = 0.0f, b1v = 0.0f;
    if (sub < HID) { w1v = W1[sub]; b1v = b1[sub]; }

    const int gwave  = (blockIdx.x << 2) + (tid >> 6);
    const int nwaves = gridDim.x << 2;
    const int nwU    = nwaves * UNROLL;
    const int npair  = (n_tokens + 1) >> 1;
    const int tmax   = n_tokens - 1;

    for (int w = gwave; w < npair; w += nwU) {
        int   tok[UNROLL];
        bool  act[UNROLL];
        float v[UNROLL];
        int   id[UNROLL];
        float fm[UNROLL];

#pragma unroll
        for (int k = 0; k < UNROLL; ++k) {
            const int wk = w + k * nwaves;
            act[k] = (wk < npair);
            int t = 2 * wk + half;
            if (t > tmax) t = tmax;
            tok[k] = t;
            v[k]  = value[t];
            id[k] = var_id[t];
            fm[k] = (float)cmask[t];
        }

        f32x4 e[UNROLL];
#pragma unroll
        for (int k = 0; k < UNROLL; ++k)
            e[k] = *reinterpret_cast<const f32x4*>(emb + (long)id[k] * EMB + c0);

        float hv[UNROLL];
#pragma unroll
        for (int k = 0; k < UNROLL; ++k)
            hv[k] = fast_tanh(fmaf(v[k], w1v, b1v));

        f32x4 acc[UNROLL];
#pragma unroll
        for (int k = 0; k < UNROLL; ++k)
            acc[k] = (f32x4){0.f, 0.f, 0.f, 0.f};

#pragma unroll
        for (int hh = 0; hh < HID; ++hh) {
#pragma unroll
            for (int k = 0; k < UNROLL; ++k) {
                const float kk = __shfl(hv[k], sb + hh, 64);
                acc[k] += kk * w2[hh];
            }
        }

#pragma unroll
        for (int k = 0; k < UNROLL; ++k) {
            if (!act[k]) continue;
            const f32x4 o = acc[k] * fm[k] + e[k];
            __builtin_nontemporal_store(o,
                reinterpret_cast<f32x4*>(out_sum + (long)tok[k] * EMB + c0));
            if (sub == 0)
                out_pm[tok[k]] = (id[k] > 0) ? 1.0f : 0.0f;
        }
    }
}

extern "C" void kernel_launch(void* const* d_in, const int* in_sizes, int n_in,
                              void* d_out, int out_size, void* d_ws, size_t ws_size,
                              hipStream_t stream) {
    const float* value  = (const float*)d_in[0];
    const int*   var_id = (const int*)  d_in[1];
    const int*   cmask  = (const int*)  d_in[2];
    const float* W1     = (const float*)d_in[3];
    const float* b1     = (const float*)d_in[4];
    const float* W2     = (const float*)d_in[5];
    const float* emb    = (const float*)d_in[6];

    const int n_tokens = in_sizes[0];              // 4096*200 = 819200
    float* out_sum = (float*)d_out;                // [n_tokens, 128]
    float* out_pm  = (float*)d_out + (long long)n_tokens * EMB;  // [n_tokens]

    const int waves_needed  = (n_tokens + 1) / 2;
    const int blocks_needed = (waves_needed + 3) / 4;
    const int grid = blocks_needed < 2048 ? blocks_needed : 2048;

    tabenc_kernel<<<grid, 256, 0, stream>>>(value, var_id, cmask, W1, b1, W2,
                                            emb, out_sum, out_pm, n_tokens);
}

// Round 5
// 95.450 us; speedup vs baseline: 2.8909x; 1.0241x over previous
//
#include <hip/hip_runtime.h>
#include <hip/hip_bf16.h>

#define EMB 128
#define HID 11
#define PAIRS 2   // token-pairs per pipeline stage (4 tokens/stage)

typedef float f32x4 __attribute__((ext_vector_type(4)));

// tanh(x) = sign(x) * (1 - 2/(exp(2|x|)+1)); v_exp_f32 + v_rcp_f32 fast path.
__device__ __forceinline__ float fast_tanh(float x) {
    float ax = fabsf(x);
    float e  = __expf(2.0f * ax);
    float r  = 1.0f - 2.0f * __builtin_amdgcn_rcpf(e + 1.0f);
    return copysignf(r, x);
}

// Wave layout: lanes 0..31 -> token 2w, lanes 32..63 -> token 2w+1; lane
// covers 4 emb columns (float4), c0 = (lane&31)*4. One fast-tanh per token,
// h broadcast via __shfl within the half-wave.
//
// R4 lesson: unroll depth alone leaves compute serialized behind the
// var_id -> emb-gather chain each iteration (~98 us = 63 mem + 35 serial).
// This version SOFTWARE-PIPELINES the grid-stride loop: next stage's scalar
// loads + gathers are issued (branch-free, clamped) before the current
// stage's FMA/store block, so the ~600cyc load chain hides under compute.
// __launch_bounds__(256,2) keeps the ~108 live VGPRs unspilled (R3 lesson).
__global__ __launch_bounds__(256, 2) void tabenc_kernel(
    const float* __restrict__ value,
    const int*   __restrict__ var_id,
    const int*   __restrict__ cmask,
    const float* __restrict__ W1,
    const float* __restrict__ b1,
    const float* __restrict__ W2,
    const float* __restrict__ emb,
    float*       __restrict__ out_sum,
    float*       __restrict__ out_pm,
    int n_tokens)
{
    const int tid  = threadIdx.x;
    const int lane = tid & 63;
    const int half = lane >> 5;
    const int sub  = lane & 31;
    const int sb   = lane & 32;      // shfl source base for this half-wave
    const int c0   = sub << 2;

    f32x4 w2[HID];
#pragma unroll
    for (int h = 0; h < HID; ++h)
        w2[h] = *reinterpret_cast<const f32x4*>(W2 + h * EMB + c0);

    float w1v = 0.0f, b1v = 0.0f;
    if (sub < HID) { w1v = W1[sub]; b1v = b1[sub]; }

    const int gwave  = (blockIdx.x << 2) + (tid >> 6);
    const int nwaves = gridDim.x << 2;
    const int nwS    = nwaves * PAIRS;      // stage stride in pair-index space
    const int npair  = (n_tokens + 1) >> 1;
    const int tmax   = n_tokens - 1;

    if (gwave >= npair) return;

    int   tokC[PAIRS]; bool actC[PAIRS]; float vC[PAIRS];
    int   idC[PAIRS];  float fmC[PAIRS];  f32x4 eC[PAIRS];
    int   tokN[PAIRS]; bool actN[PAIRS]; float vN[PAIRS];
    int   idN[PAIRS];  float fmN[PAIRS];  f32x4 eN[PAIRS];

    auto LOAD = [&](int wbase, int* tok, bool* act, float* v, int* id,
                    float* fm, f32x4* e) {
#pragma unroll
        for (int k = 0; k < PAIRS; ++k) {
            const int wk = wbase + k * nwaves;
            act[k] = (wk < npair);
            int t = 2 * wk + half;
            if (t > tmax) t = tmax;     // clamp: branch-free, dup loads only
            tok[k] = t;
            v[k]  = value[t];
            id[k] = var_id[t];
            fm[k] = (float)cmask[t];
        }
#pragma unroll
        for (int k = 0; k < PAIRS; ++k)
            e[k] = *reinterpret_cast<const f32x4*>(emb + (long)id[k] * EMB + c0);
    };

    LOAD(gwave, tokC, actC, vC, idC, fmC, eC);

    for (int w = gwave; w < npair; w += nwS) {
        // ---- prefetch next stage (clamped, unconditional) ----
        LOAD(w + nwS, tokN, actN, vN, idN, fmN, eN);

        // ---- compute current stage ----
        float hv[PAIRS];
#pragma unroll
        for (int k = 0; k < PAIRS; ++k)
            hv[k] = fast_tanh(fmaf(vC[k], w1v, b1v));

        f32x4 acc[PAIRS];
#pragma unroll
        for (int k = 0; k < PAIRS; ++k)
            acc[k] = (f32x4){0.f, 0.f, 0.f, 0.f};

#pragma unroll
        for (int hh = 0; hh < HID; ++hh) {
#pragma unroll
            for (int k = 0; k < PAIRS; ++k) {
                const float kk = __shfl(hv[k], sb + hh, 64);
                acc[k] += kk * w2[hh];
            }
        }

#pragma unroll
        for (int k = 0; k < PAIRS; ++k) {
            if (actC[k]) {
                const f32x4 o = acc[k] * fmC[k] + eC[k];
                __builtin_nontemporal_store(o,
                    reinterpret_cast<f32x4*>(out_sum + (long)tokC[k] * EMB + c0));
                if (sub == 0)
                    out_pm[tokC[k]] = (idC[k] > 0) ? 1.0f : 0.0f;
            }
        }

        // ---- rotate pipeline regs ----
#pragma unroll
        for (int k = 0; k < PAIRS; ++k) {
            tokC[k] = tokN[k]; actC[k] = actN[k]; vC[k] = vN[k];
            idC[k]  = idN[k];  fmC[k]  = fmN[k];  eC[k] = eN[k];
        }
    }
}

extern "C" void kernel_launch(void* const* d_in, const int* in_sizes, int n_in,
                              void* d_out, int out_size, void* d_ws, size_t ws_size,
                              hipStream_t stream) {
    const float* value  = (const float*)d_in[0];
    const int*   var_id = (const int*)  d_in[1];
    const int*   cmask  = (const int*)  d_in[2];
    const float* W1     = (const float*)d_in[3];
    const float* b1     = (const float*)d_in[4];
    const float* W2     = (const float*)d_in[5];
    const float* emb    = (const float*)d_in[6];

    const int n_tokens = in_sizes[0];              // 4096*200 = 819200
    float* out_sum = (float*)d_out;                // [n_tokens, 128]
    float* out_pm  = (float*)d_out + (long long)n_tokens * EMB;  // [n_tokens]

    const int waves_needed  = (n_tokens + 1) / 2;
    const int blocks_needed = (waves_needed + 3) / 4;
    const int grid = blocks_needed < 2048 ? blocks_needed : 2048;

    tabenc_kernel<<<grid, 256, 0, stream>>>(value, var_id, cmask, W1, b1, W2,
                                            emb, out_sum, out_pm, n_tokens);
}